// Round 3
// baseline (161.656 us; speedup 1.0000x reference)
//
#include <hip/hip_runtime.h>
#include <hip/hip_bf16.h>

// Problem constants: B=1, C=64 in/out, N_NODES=16384, TWO_M=1048576 -> M=524288 edges.
#define C_DIM 64
#define N_NODES 16384
#define M_EDGES 524288

// out[:,n] = cnt[n] * (W0@seq)[:,n] + sum_{edges m with u_m==n} (W1@seq)[:, v_m]
// K1 k_gemm : register-blocked fp32; P = W0@seq (into d_out, [o][n]), Tt = (W1@seq)^T ([n][o]).
// K2 k_count: histogram cnt[u] (int atomics, 2 edges/thread).
// K3 k_scan : coalesced exclusive prefix sum cnt -> rowstart; also zeroes cursor.
// K4 k_fill : CSR edge list elist[rowstart[u]+cursor[u]++] = v (2 edges/thread).
// K5 k_gather: per-node gather-sum of Tt rows (atomic-free, L2-resident, 8-deep ILP)
//              + fused transpose epilogue out[o][n] = gather + cnt[n]*P[o][n].

__global__ __launch_bounds__(256)
void k_gemm(const float* __restrict__ seq, const float* __restrict__ W,
            float* __restrict__ P, float* __restrict__ Tt) {
    __shared__ float Wl[1024];         // [k][ol][c] : k*512 + ol*64 + c
    const int n0 = blockIdx.x * 512;
    const int o0 = blockIdx.y * 8;
    const int t  = threadIdx.x;
    const int nb = n0 + 2 * t;         // this thread's 2 nodes

    // Stage W slice: Wl[k*512 + ol*64 + c] = W[(o0+ol)*128 + c*2 + k]
    #pragma unroll
    for (int i = 0; i < 4; ++i) {
        int e  = t + 256 * i;          // e = (k<<9)|(ol<<6)|c
        int c  = e & 63;
        int ol = (e >> 6) & 7;
        int k  = e >> 9;
        Wl[e] = W[(o0 + ol) * 128 + c * 2 + k];
    }
    __syncthreads();

    const float4* Wl4 = (const float4*)Wl;
    float2 acc0[8], acc1[8];
    #pragma unroll
    for (int i = 0; i < 8; ++i) { acc0[i] = make_float2(0.f, 0.f); acc1[i] = make_float2(0.f, 0.f); }

    #pragma unroll 4
    for (int c4 = 0; c4 < 16; ++c4) {
        const int c = c4 * 4;
        float2 s0 = *(const float2*)(seq + (size_t)(c + 0) * N_NODES + nb);
        float2 s1 = *(const float2*)(seq + (size_t)(c + 1) * N_NODES + nb);
        float2 s2 = *(const float2*)(seq + (size_t)(c + 2) * N_NODES + nb);
        float2 s3 = *(const float2*)(seq + (size_t)(c + 3) * N_NODES + nb);
        #pragma unroll
        for (int ol = 0; ol < 8; ++ol) {
            float4 w0 = Wl4[ol * 16 + c4];        // k = 0, c..c+3
            float4 w1 = Wl4[128 + ol * 16 + c4];  // k = 1
            acc0[ol].x += w0.x * s0.x + w0.y * s1.x + w0.z * s2.x + w0.w * s3.x;
            acc0[ol].y += w0.x * s0.y + w0.y * s1.y + w0.z * s2.y + w0.w * s3.y;
            acc1[ol].x += w1.x * s0.x + w1.y * s1.x + w1.z * s2.x + w1.w * s3.x;
            acc1[ol].y += w1.x * s0.y + w1.y * s1.y + w1.z * s2.y + w1.w * s3.y;
        }
    }

    // P[o][n]: coalesced float2 stores.
    #pragma unroll
    for (int ol = 0; ol < 8; ++ol) {
        *(float2*)(P + (size_t)(o0 + ol) * N_NODES + nb) = acc0[ol];
    }
    // Tt[n][o]: 8 consecutive o per n -> two float4 stores per node.
    float4 a = make_float4(acc1[0].x, acc1[1].x, acc1[2].x, acc1[3].x);
    float4 b = make_float4(acc1[4].x, acc1[5].x, acc1[6].x, acc1[7].x);
    float4 cda = make_float4(acc1[0].y, acc1[1].y, acc1[2].y, acc1[3].y);
    float4 cdb = make_float4(acc1[4].y, acc1[5].y, acc1[6].y, acc1[7].y);
    *(float4*)(Tt + (size_t)nb * C_DIM + o0)     = a;
    *(float4*)(Tt + (size_t)nb * C_DIM + o0 + 4) = b;
    *(float4*)(Tt + (size_t)(nb + 1) * C_DIM + o0)     = cda;
    *(float4*)(Tt + (size_t)(nb + 1) * C_DIM + o0 + 4) = cdb;
}

__global__ void k_count(const int* __restrict__ idx, int* __restrict__ cnt) {
    const int g = blockIdx.x * 256 + threadIdx.x;
    int4 p = ((const int4*)idx)[g];
    atomicAdd(&cnt[p.x], 1);
    atomicAdd(&cnt[p.z], 1);
}

__global__ __launch_bounds__(1024)
void k_scan(const int* __restrict__ cnt, int* __restrict__ rowstart, int* __restrict__ cursor) {
    __shared__ int sh[N_NODES];        // 64 KB
    __shared__ int wsum[16];
    const int t = threadIdx.x;         // 1024 threads
    const int lane = t & 63, wv = t >> 6;
    #pragma unroll
    for (int i = 0; i < 16; ++i) sh[t + 1024 * i] = cnt[t + 1024 * i];   // coalesced
    __syncthreads();
    int local[16];
    int s = 0;
    #pragma unroll
    for (int i = 0; i < 16; ++i) { local[i] = sh[t * 16 + i]; s += local[i]; }
    int x = s;  // inclusive wave scan
    #pragma unroll
    for (int d = 1; d < 64; d <<= 1) {
        int y = __shfl_up(x, (unsigned)d);
        if (lane >= d) x += y;
    }
    __syncthreads();
    if (lane == 63) wsum[wv] = x;
    __syncthreads();
    if (t == 0) {
        int acc = 0;
        #pragma unroll
        for (int i = 0; i < 16; ++i) { int v = wsum[i]; wsum[i] = acc; acc += v; }
    }
    __syncthreads();
    int base = wsum[wv] + (x - s);     // exclusive prefix of this thread's chunk
    #pragma unroll
    for (int i = 0; i < 16; ++i) { sh[t * 16 + i] = base; base += local[i]; }
    __syncthreads();
    #pragma unroll
    for (int i = 0; i < 16; ++i) rowstart[t + 1024 * i] = sh[t + 1024 * i]; // coalesced
    #pragma unroll
    for (int i = 0; i < 16; ++i) cursor[t + 1024 * i] = 0;
}

__global__ void k_fill(const int* __restrict__ idx, const int* __restrict__ rowstart,
                       int* __restrict__ cursor, int* __restrict__ elist) {
    const int g = blockIdx.x * 256 + threadIdx.x;
    int4 p = ((const int4*)idx)[g];
    int pos0 = atomicAdd(&cursor[p.x], 1);
    elist[rowstart[p.x] + pos0] = p.y;
    int pos1 = atomicAdd(&cursor[p.z], 1);
    elist[rowstart[p.z] + pos1] = p.w;
}

__global__ __launch_bounds__(256)
void k_gather(const int* __restrict__ rowstart, const int* __restrict__ cnt,
              const int* __restrict__ elist, const float* __restrict__ Tt,
              float* __restrict__ out) {
    __shared__ float Atile[32 * 65];  // [n_local][o] padded
    const int n0 = blockIdx.x * 32;
    const int t  = threadIdx.x;
    const int o  = t & 63;
    const int wv = t >> 6;            // 0..3

    #pragma unroll
    for (int s = 0; s < 8; ++s) {
        const int nl = wv + 4 * s;
        const int n  = n0 + nl;
        const int base = rowstart[n];
        const int d    = cnt[n];
        float acc = 0.f;
        for (int jb = 0; jb < d; jb += 64) {
            const int chunk = min(64, d - jb);
            int vv = 0;
            if (o < chunk) vv = elist[base + jb + o];
            int j = 0;
            for (; j + 8 <= chunk; j += 8) {
                int v0 = __shfl(vv, j);
                int v1 = __shfl(vv, j + 1);
                int v2 = __shfl(vv, j + 2);
                int v3 = __shfl(vv, j + 3);
                int v4 = __shfl(vv, j + 4);
                int v5 = __shfl(vv, j + 5);
                int v6 = __shfl(vv, j + 6);
                int v7 = __shfl(vv, j + 7);
                float a0 = Tt[v0 * C_DIM + o];
                float a1 = Tt[v1 * C_DIM + o];
                float a2 = Tt[v2 * C_DIM + o];
                float a3 = Tt[v3 * C_DIM + o];
                float a4 = Tt[v4 * C_DIM + o];
                float a5 = Tt[v5 * C_DIM + o];
                float a6 = Tt[v6 * C_DIM + o];
                float a7 = Tt[v7 * C_DIM + o];
                acc += a0; acc += a1; acc += a2; acc += a3;
                acc += a4; acc += a5; acc += a6; acc += a7;
            }
            for (; j < chunk; ++j) {
                int v = __shfl(vv, j);
                acc += Tt[v * C_DIM + o];
            }
        }
        Atile[nl * 65 + o] = acc;
    }
    __syncthreads();
    // Fused epilogue: out[o][n] = Atile[n][o] + cnt[n] * P[o][n]  (P lives in d_out)
    const int nl = t & 31;
    const int ob = t >> 5;            // 0..7
    const float cn = (float)cnt[n0 + nl];
    #pragma unroll
    for (int j = 0; j < 8; ++j) {
        int o2 = ob + 8 * j;
        size_t gi = (size_t)o2 * N_NODES + n0 + nl;
        float p = out[gi];
        out[gi] = Atile[nl * 65 + o2] + cn * p;
    }
}

extern "C" void kernel_launch(void* const* d_in, const int* in_sizes, int n_in,
                              void* d_out, int out_size, void* d_ws, size_t ws_size,
                              hipStream_t stream) {
    const float* seq = (const float*)d_in[0];
    const int*   idx = (const int*)d_in[1];
    const float* W   = (const float*)d_in[2];
    float* out = (float*)d_out;

    // ws layout: Tt [N*64 f32] | cnt [N] | cursor [N] | rowstart [N] | elist [M]  (~6.3 MB)
    float* Tt       = (float*)d_ws;
    int*   cnt      = (int*)(Tt + (size_t)N_NODES * C_DIM);
    int*   cursor   = cnt + N_NODES;
    int*   rowstart = cursor + N_NODES;
    int*   elist    = rowstart + N_NODES;

    hipMemsetAsync(cnt, 0, N_NODES * sizeof(int), stream);  // cursor zeroed in k_scan

    k_gemm<<<dim3(N_NODES / 512, C_DIM / 8), 256, 0, stream>>>(seq, W, out, Tt);
    k_count<<<M_EDGES / 2 / 256, 256, 0, stream>>>(idx, cnt);
    k_scan<<<1, 1024, 0, stream>>>(cnt, rowstart, cursor);
    k_fill<<<M_EDGES / 2 / 256, 256, 0, stream>>>(idx, rowstart, cursor, elist);
    k_gather<<<N_NODES / 32, 256, 0, stream>>>(rowstart, cnt, elist, Tt, out);
}